// Round 4
// baseline (105.485 us; speedup 1.0000x reference)
//
#include <hip/hip_runtime.h>
#include <hip/hip_bf16.h>

typedef __bf16 bf16_t;
typedef bf16_t bf16x8 __attribute__((ext_vector_type(8)));
typedef bf16_t bf16x4 __attribute__((ext_vector_type(4)));
typedef float  floatx4 __attribute__((ext_vector_type(4)));

#define NROWS 65536
#define NCENT 512
#define NDIM  128
#define NBLK  256
#define TROWS 64
#define NTILE 4          // NBLK * TROWS * NTILE == NROWS
#define ZPITCH 136       // 128 + 8 bf16 pad: 16B-aligned rows, free 2-way bank aliasing

// LDS phase 1: muf[512*128] bf16 frag-major (128 KB)
//   frag addr(col,k) = c*8192 + g*2048 + kk*512 + quad*128 + c16*8 + e
//   col = c*64+g*16+c16, k = kk*32+quad*8+e  -> wave-w B-frag b128 reads conflict-free
// LDS phase 2 (overlaid): ztile[64*ZPITCH] (17408 B) | z2s[64] | rmx[64][8]

__global__ __launch_bounds__(512, 2)
void kmeans_fused(const float* __restrict__ z, const float* __restrict__ mu,
                  float* __restrict__ out)
{
    __shared__ __align__(16) unsigned char smem[131072];
    __shared__ float h2s[NCENT];

    bf16_t* muf   = (bf16_t*)smem;
    bf16_t* ztile = (bf16_t*)smem;
    float*  z2s   = (float*)(smem + 17408);
    float*  rmx   = (float*)(smem + 17664);   // [row][wave] = [64][8]

    const int tid  = threadIdx.x;
    const int lane = tid & 63;
    const int w    = tid >> 6;      // wave 0..7 owns cols w*64 .. w*64+63
    const int quad = lane >> 4;
    const int l16  = lane & 15;

    // ---- prefetch z tile 0 now; HBM latency overlaps the mu pack phase ----
    float4 pf[4];
    {
        const float4* zsrc = (const float4*)(z + (size_t)blockIdx.x * TROWS * NDIM);
#pragma unroll
        for (int i = 0; i < 2; ++i) {
            int q8 = i * 512 + tid;
            pf[2*i]   = zsrc[q8 * 2];
            pf[2*i+1] = zsrc[q8 * 2 + 1];
        }
    }

    // ---- pack mu fp32 -> bf16 frag-major in LDS, + h2 = 0.5*|mu_bf16|^2 ----
    {
        const float4* msrc = (const float4*)mu;
#pragma unroll
        for (int p = 0; p < 32; ++p) {
            int q = p * 512 + tid;              // float4 index over 512*128 floats
            float4 v = msrc[q];
            int col = q >> 5;                   // 32 float4 per col
            int k0  = (q & 31) << 2;
            bf16x4 pk = {(bf16_t)v.x, (bf16_t)v.y, (bf16_t)v.z, (bf16_t)v.w};
            int c = col >> 6, g = (col >> 4) & 3, c16 = col & 15;
            int kk = k0 >> 5, qd = (k0 >> 3) & 3, e0 = k0 & 7;
            *(bf16x4*)&muf[c*8192 + g*2048 + kk*512 + qd*128 + c16*8 + e0] = pk;
            float f0=(float)pk[0], f1=(float)pk[1], f2=(float)pk[2], f3=(float)pk[3];
            float s = f0*f0 + f1*f1 + f2*f2 + f3*f3;
            s += __shfl_xor(s, 1); s += __shfl_xor(s, 2); s += __shfl_xor(s, 4);
            s += __shfl_xor(s, 8); s += __shfl_xor(s, 16);
            if ((tid & 31) == 0) h2s[col] = 0.5f * s;   // col unique per (p, tid>>5)
        }
    }
    __syncthreads();

    // ---- hoist this wave's B fragments + h2 into registers (live all kernel) ----
    bf16x8 bfr[4][4];
    float  h2v[4];
#pragma unroll
    for (int j2 = 0; j2 < 4; ++j2) {
#pragma unroll
        for (int kk = 0; kk < 4; ++kk)
            bfr[j2][kk] = *(const bf16x8*)&muf[w*8192 + j2*2048 + kk*512 + quad*128 + l16*8];
        h2v[j2] = h2s[w*64 + j2*16 + l16];
    }
    __syncthreads();   // frag reads done -> muf space reusable as ztile

    float fsum = 0.f;

    for (int t = 0; t < NTILE; ++t) {
        // ---- stage ztile (cvt fp32->bf16) + per-row z2 from rounded values ----
#pragma unroll
        for (int i = 0; i < 2; ++i) {
            int q8 = i * 512 + tid;             // 8-float unit; 16 per row
            float4 va = pf[2*i], vb = pf[2*i+1];
            int r = q8 >> 4, c8 = (q8 & 15) << 3;
            bf16x8 pk = {(bf16_t)va.x, (bf16_t)va.y, (bf16_t)va.z, (bf16_t)va.w,
                         (bf16_t)vb.x, (bf16_t)vb.y, (bf16_t)vb.z, (bf16_t)vb.w};
            *(bf16x8*)&ztile[r * ZPITCH + c8] = pk;
            float ss = 0.f;
#pragma unroll
            for (int e = 0; e < 8; ++e) { float f = (float)pk[e]; ss = fmaf(f, f, ss); }
            ss += __shfl_xor(ss, 1); ss += __shfl_xor(ss, 2);
            ss += __shfl_xor(ss, 4); ss += __shfl_xor(ss, 8);
            if ((tid & 15) == 0) z2s[r] = ss;
        }
        __syncthreads();   // B1: ztile + z2s visible

        // ---- prefetch tile t+1 (drains under the MFMA phase) ----
        if (t + 1 < NTILE) {
            const float4* zsrc =
                (const float4*)(z + ((size_t)(t + 1) * NBLK + blockIdx.x) * TROWS * NDIM);
#pragma unroll
            for (int i = 0; i < 2; ++i) {
                int q8 = i * 512 + tid;
                pf[2*i]   = zsrc[q8 * 2];
                pf[2*i+1] = zsrc[q8 * 2 + 1];
            }
        }

        // ---- A fragments: all 64 rows (16 b128 reads), then pure MFMA stream ----
        bf16x8 afr[4][4];
#pragma unroll
        for (int i = 0; i < 4; ++i)
#pragma unroll
            for (int kk = 0; kk < 4; ++kk)
                afr[i][kk] = *(const bf16x8*)&ztile[(i*16 + l16) * ZPITCH + kk*32 + quad*8];

        float tm[4][4];
#pragma unroll
        for (int i = 0; i < 4; ++i)
#pragma unroll
            for (int r = 0; r < 4; ++r) tm[i][r] = -3.0e38f;

#pragma unroll
        for (int j2 = 0; j2 < 4; ++j2) {
#pragma unroll
            for (int i = 0; i < 4; ++i) {      // 4 independent acc chains -> ILP
                floatx4 acc = (floatx4){0.f, 0.f, 0.f, 0.f};
#pragma unroll
                for (int kk = 0; kk < 4; ++kk)
                    acc = __builtin_amdgcn_mfma_f32_16x16x32_bf16(
                        afr[i][kk], bfr[j2][kk], acc, 0, 0, 0);
#pragma unroll
                for (int r = 0; r < 4; ++r)
                    tm[i][r] = fmaxf(tm[i][r], acc[r] - h2v[j2]);  // deferred sqrt
            }
        }

        // ---- per-row max over this wave's 64 cols, publish per wave ----
#pragma unroll
        for (int i = 0; i < 4; ++i)
#pragma unroll
            for (int r = 0; r < 4; ++r) {
                float v = tm[i][r];
                v = fmaxf(v, __shfl_xor(v, 1));
                v = fmaxf(v, __shfl_xor(v, 2));
                v = fmaxf(v, __shfl_xor(v, 4));
                v = fmaxf(v, __shfl_xor(v, 8));
                if (l16 == 0) rmx[(i*16 + quad*4 + r) * 8 + w] = v;
            }
        __syncthreads();   // B2: rmx visible

        if (tid < TROWS) {
            float m = rmx[tid * 8];
#pragma unroll
            for (int k = 1; k < 8; ++k) m = fmaxf(m, rmx[tid * 8 + k]);
            float d2 = z2s[tid] - 2.0f * m;
            fsum += sqrtf(fmaxf(d2, 0.f));     // one sqrt per row
        }
        __syncthreads();   // B3: protect ztile/z2s/rmx for next tile
    }

    // ---- wave 0 holds the 64 row-sums; reduce + one atomic per block ----
    if (w == 0) {
        float v = fsum;
#pragma unroll
        for (int off = 32; off; off >>= 1) v += __shfl_down(v, off);
        if (tid == 0) atomicAdd(out, v * (1.0f / 65536.0f));
    }
}

extern "C" void kernel_launch(void* const* d_in, const int* in_sizes, int n_in,
                              void* d_out, int out_size, void* d_ws, size_t ws_size,
                              hipStream_t stream) {
    const float* z  = (const float*)d_in[0];
    const float* mu = (const float*)d_in[1];
    float* out = (float*)d_out;
    hipMemsetAsync(out, 0, sizeof(float), stream);   // d_out is poisoned 0xAA
    kmeans_fused<<<dim3(NBLK), dim3(512), 0, stream>>>(z, mu, out);
}